// Round 1
// baseline (4630.616 us; speedup 1.0000x reference)
//
#include <hip/hip_runtime.h>
#include <math.h>

#define BATCH 16
#define CIN   128
#define HID   128
#define HDIM  64
#define WDIM  64

// ---------------------------------------------------------------------------
// Pack kernel: reorder weights for wave-uniform contiguous scalar fetch.
//   Wis_p[c][hid][gate][tap2] : taps 0,1 (tap 2 masked to zero by 'B' mask)
//   Wss_p[c][hid][gate][tap3]
//   bias_p[hid][gate] = b_is + b_ss
// Original layouts: W_is/W_ss = [o=gate*128+hid][c][1][3], b = [512]
// ---------------------------------------------------------------------------
__global__ void pack_kernel(const float* __restrict__ W_is,
                            const float* __restrict__ b_is,
                            const float* __restrict__ W_ss,
                            const float* __restrict__ b_ss,
                            float* __restrict__ Wis_p,
                            float* __restrict__ Wss_p,
                            float* __restrict__ bias_p) {
    int idx = blockIdx.x * blockDim.x + threadIdx.x;

    // Wis_p: 128*128*4*2 = 131072 entries. idx = ((c*128+h)*4+g)*2+t
    if (idx < CIN * HID * 4 * 2) {
        int t = idx & 1;
        int g = (idx >> 1) & 3;
        int h = (idx >> 3) & 127;
        int c = idx >> 10;
        Wis_p[idx] = W_is[((g * HID + h) * CIN + c) * 3 + t];
    }
    // Wss_p: 128*128*4*3 = 196608 entries. idx = ((c*128+h)*4+g)*3+t
    if (idx < CIN * HID * 4 * 3) {
        int t = idx % 3;
        int rest = idx / 3;              // (c*128+h)*4+g
        int g = rest & 3;
        int h = (rest >> 2) & 127;
        int c = rest >> 9;
        Wss_p[idx] = W_ss[((g * HID + h) * CIN + c) * 3 + t];
    }
    // bias: 512 entries. idx = h*4+g
    if (idx < HID * 4) {
        int g = idx & 3;
        int h = idx >> 2;
        bias_p[idx] = b_is[g * HID + h] + b_ss[g * HID + h];
    }
}

// ---------------------------------------------------------------------------
// Row kernel: one LSTM row step for all batches.
// Grid: 256 blocks x 256 threads = 1024 waves.
//   wave -> (b, hid pair), lane -> w (W=64 == wavefront size).
// Each thread accumulates z for 2 hid channels x 4 gates at its w.
// Conv taps via wave shuffles (zero-padded at w edges).
// ---------------------------------------------------------------------------
__global__ __launch_bounds__(256) void row_kernel(
        const float* __restrict__ x,
        const float* __restrict__ Wis_p,
        const float* __restrict__ Wss_p,
        const float* __restrict__ bias_p,
        float* __restrict__ c_state,
        float* __restrict__ out,
        int r) {
    int wave = (blockIdx.x * blockDim.x + threadIdx.x) >> 6;   // 0..1023
    int w    = threadIdx.x & 63;                               // lane = w
    int b    = __builtin_amdgcn_readfirstlane(wave >> 6);      // 0..15
    int hb   = __builtin_amdgcn_readfirstlane((wave & 63) * 2);// hid base (2 ch)

    float acc[2][4];
#pragma unroll
    for (int l = 0; l < 2; ++l)
#pragma unroll
        for (int g = 0; g < 4; ++g) acc[l][g] = 0.0f;

    // ---- input-to-state: taps (w-1, w), K = 128 channels ----
    const float* xrow = x + (size_t)b * CIN * HDIM * WDIM + (size_t)r * WDIM;
#pragma unroll 4
    for (int c = 0; c < CIN; ++c) {
        float xv = xrow[c * (HDIM * WDIM) + w];
        float xl = __shfl_up(xv, 1);
        if (w == 0) xl = 0.0f;
        const float* wx = Wis_p + c * (HID * 4 * 2) + hb * (4 * 2);
#pragma unroll
        for (int l = 0; l < 2; ++l)
#pragma unroll
            for (int g = 0; g < 4; ++g) {
                acc[l][g] += wx[(l * 4 + g) * 2 + 0] * xl
                           + wx[(l * 4 + g) * 2 + 1] * xv;
            }
    }

    // ---- state-to-state: taps (w-1, w, w+1) on h_prev, K = 128 channels ----
    if (r > 0) {
        const float* hrow = out + (size_t)b * HID * HDIM * WDIM
                                + (size_t)(r - 1) * WDIM;
#pragma unroll 4
        for (int c = 0; c < HID; ++c) {
            float hv = hrow[c * (HDIM * WDIM) + w];
            float hl = __shfl_up(hv, 1);
            if (w == 0) hl = 0.0f;
            float hr = __shfl_down(hv, 1);
            if (w == 63) hr = 0.0f;
            const float* wh = Wss_p + c * (HID * 4 * 3) + hb * (4 * 3);
#pragma unroll
            for (int l = 0; l < 2; ++l)
#pragma unroll
                for (int g = 0; g < 4; ++g) {
                    acc[l][g] += wh[(l * 4 + g) * 3 + 0] * hl
                               + wh[(l * 4 + g) * 3 + 1] * hv
                               + wh[(l * 4 + g) * 3 + 2] * hr;
                }
        }
    }

    // ---- gates + LSTM state update ----
#pragma unroll
    for (int l = 0; l < 2; ++l) {
        int hc = hb + l;
        float zi = acc[l][0] + bias_p[hc * 4 + 0];
        float zf = acc[l][1] + bias_p[hc * 4 + 1];
        float zo = acc[l][2] + bias_p[hc * 4 + 2];
        float zg = acc[l][3] + bias_p[hc * 4 + 3];
        float ig = 1.0f / (1.0f + __expf(-zi));
        float fg = 1.0f / (1.0f + __expf(-zf));
        float og = 1.0f / (1.0f + __expf(-zo));
        float gg = tanhf(zg);
        size_t cidx = ((size_t)b * HID + hc) * WDIM + w;
        float cold = (r == 0) ? 0.0f : c_state[cidx];
        float cnew = fg * cold + ig * gg;
        c_state[cidx] = cnew;
        out[((size_t)b * HID + hc) * (HDIM * WDIM) + (size_t)r * WDIM + w]
            = og * tanhf(cnew);
    }
}

extern "C" void kernel_launch(void* const* d_in, const int* in_sizes, int n_in,
                              void* d_out, int out_size, void* d_ws, size_t ws_size,
                              hipStream_t stream) {
    const float* x    = (const float*)d_in[0];
    const float* W_is = (const float*)d_in[1];
    const float* b_is = (const float*)d_in[2];
    const float* W_ss = (const float*)d_in[3];
    const float* b_ss = (const float*)d_in[4];
    float* out = (float*)d_out;
    float* ws  = (float*)d_ws;

    // ws layout (floats): c_state[131072] | Wis_p[131072] | Wss_p[196608] | bias_p[512]
    float* c_state = ws;
    float* Wis_p   = ws + 131072;
    float* Wss_p   = ws + 131072 + 131072;
    float* bias_p  = ws + 131072 + 131072 + 196608;

    pack_kernel<<<(CIN * HID * 4 * 3 + 255) / 256, 256, 0, stream>>>(
        W_is, b_is, W_ss, b_ss, Wis_p, Wss_p, bias_p);

    for (int r = 0; r < HDIM; ++r) {
        row_kernel<<<256, 256, 0, stream>>>(
            x, Wis_p, Wss_p, bias_p, c_state, out, r);
    }
}

// Round 2
// 1803.937 us; speedup vs baseline: 2.5669x; 2.5669x over previous
//
#include <hip/hip_runtime.h>
#include <math.h>

#define BATCH 16
#define CIN   128
#define HID   128
#define HDIM  64
#define WDIM  64

// ---------------------------------------------------------------------------
// Pack kernel: reorder weights so each wave (= one hid channel) reads small
// contiguous wave-uniform chunks per c (scalar loads, parallel to VALU).
//   Wis_p[h][c][g][t2]  (8 floats / c)   taps 0,1 ('B' mask zeroes tap 2)
//   Wss_p[h][c][g][t3]  (12 floats / c)
//   bias_p[h][g] = b_is + b_ss
// Original: W_is/W_ss = [o=g*128+h][c][1][3], b = [512]
// ---------------------------------------------------------------------------
__global__ void pack_kernel(const float* __restrict__ W_is,
                            const float* __restrict__ b_is,
                            const float* __restrict__ W_ss,
                            const float* __restrict__ b_ss,
                            float* __restrict__ Wis_p,
                            float* __restrict__ Wss_p,
                            float* __restrict__ bias_p) {
    int idx = blockIdx.x * blockDim.x + threadIdx.x;

    // Wis_p: 128*128*4*2 = 131072.  idx = ((h*128+c)*4+g)*2+t
    if (idx < HID * CIN * 4 * 2) {
        int t = idx & 1;
        int g = (idx >> 1) & 3;
        int c = (idx >> 3) & 127;
        int h = idx >> 10;
        Wis_p[idx] = W_is[((g * HID + h) * CIN + c) * 3 + t];
    }
    // Wss_p: 128*128*4*3 = 196608.  idx = ((h*128+c)*4+g)*3+t
    if (idx < HID * CIN * 4 * 3) {
        int t = idx % 3;
        int rest = idx / 3;              // (h*128+c)*4+g
        int g = rest & 3;
        int c = (rest >> 2) & 127;
        int h = rest >> 9;
        Wss_p[idx] = W_ss[((g * HID + h) * CIN + c) * 3 + t];
    }
    // bias: 512.  idx = h*4+g
    if (idx < HID * 4) {
        int g = idx & 3;
        int h = idx >> 2;
        bias_p[idx] = b_is[g * HID + h] + b_ss[g * HID + h];
    }
}

// ---------------------------------------------------------------------------
// Row kernel v2: one LSTM row step.
// Grid: 512 blocks x 256 threads = 2048 waves = 8 waves/CU.
//   wave -> (b, hid channel), lane -> w (W = 64 = wave width).
// Key trick: the conv is linear, so accumulate per-TAP sums S_t[w] with NO
// cross-lane access in the K-loop, then combine with 2 shuffles per gate at
// the end:  z[w] = S0[w-1] + S1[w] + S2[w+1].
// 12 independent accumulators give the ILP to hide load latency.
// ---------------------------------------------------------------------------
__global__ __launch_bounds__(256, 2) void row_kernel(
        const float* __restrict__ x,
        const float* __restrict__ Wis_p,
        const float* __restrict__ Wss_p,
        const float* __restrict__ bias_p,
        float* __restrict__ c_state,
        float* __restrict__ out,
        int r) {
    int wave = (blockIdx.x * blockDim.x + threadIdx.x) >> 6;   // 0..2047
    int w    = threadIdx.x & 63;
    int b    = __builtin_amdgcn_readfirstlane(wave >> 7);      // 0..15
    int hch  = __builtin_amdgcn_readfirstlane(wave & 127);     // 0..127

    // acc_u: contributions that belong at w+1 (read via shfl_up at the end)
    // acc_c: center tap;  acc_d: contributions that belong at w-1 (shfl_down)
    float acc_u[4] = {0.f, 0.f, 0.f, 0.f};
    float acc_c[4] = {0.f, 0.f, 0.f, 0.f};
    float acc_d[4] = {0.f, 0.f, 0.f, 0.f};

    // ---- input-to-state: taps (t=0 -> x[w-1], t=1 -> x[w]) ----
    const float* xp  = x + ((size_t)b * CIN * HDIM + r) * WDIM + w;
    const float* wis = Wis_p + (size_t)hch * CIN * 8;
#pragma unroll 4
    for (int c = 0; c < CIN; ++c) {
        float xv = xp[c * (HDIM * WDIM)];
        const float* wp = wis + c * 8;
#pragma unroll
        for (int g = 0; g < 4; ++g) {
            acc_u[g] = fmaf(wp[g * 2 + 0], xv, acc_u[g]);
            acc_c[g] = fmaf(wp[g * 2 + 1], xv, acc_c[g]);
        }
    }

    // ---- state-to-state: taps (t=0 -> h[w-1], t=1 -> h[w], t=2 -> h[w+1]) ----
    if (r > 0) {
        const float* hp  = out + ((size_t)b * HID * HDIM + (r - 1)) * WDIM + w;
        const float* wss = Wss_p + (size_t)hch * CIN * 12;
#pragma unroll 4
        for (int c = 0; c < CIN; ++c) {
            float hv = hp[c * (HDIM * WDIM)];
            const float* wp = wss + c * 12;
#pragma unroll
            for (int g = 0; g < 4; ++g) {
                acc_u[g] = fmaf(wp[g * 3 + 0], hv, acc_u[g]);
                acc_c[g] = fmaf(wp[g * 3 + 1], hv, acc_c[g]);
                acc_d[g] = fmaf(wp[g * 3 + 2], hv, acc_d[g]);
            }
        }
    }

    // ---- combine taps: 2 shuffles per gate, total 8 per wave per row ----
    float z[4];
#pragma unroll
    for (int g = 0; g < 4; ++g) {
        float zu = __shfl_up(acc_u[g], 1);    // S0 evaluated at w-1
        if (w == 0) zu = 0.0f;
        float zd = __shfl_down(acc_d[g], 1);  // S2 evaluated at w+1
        if (w == 63) zd = 0.0f;
        z[g] = acc_c[g] + zu + zd + bias_p[hch * 4 + g];
    }

    // ---- LSTM update (this wave owns all 4 gates of channel hch) ----
    float ig = 1.0f / (1.0f + __expf(-z[0]));
    float fg = 1.0f / (1.0f + __expf(-z[1]));
    float og = 1.0f / (1.0f + __expf(-z[2]));
    float gg = tanhf(z[3]);

    size_t cidx = ((size_t)b * HID + hch) * WDIM + w;
    float cold = (r == 0) ? 0.0f : c_state[cidx];
    float cnew = fg * cold + ig * gg;
    c_state[cidx] = cnew;
    out[((size_t)b * HID + hch) * (HDIM * WDIM) + (size_t)r * WDIM + w]
        = og * tanhf(cnew);
}

extern "C" void kernel_launch(void* const* d_in, const int* in_sizes, int n_in,
                              void* d_out, int out_size, void* d_ws, size_t ws_size,
                              hipStream_t stream) {
    const float* x    = (const float*)d_in[0];
    const float* W_is = (const float*)d_in[1];
    const float* b_is = (const float*)d_in[2];
    const float* W_ss = (const float*)d_in[3];
    const float* b_ss = (const float*)d_in[4];
    float* out = (float*)d_out;
    float* ws  = (float*)d_ws;

    // ws layout (floats): c_state[131072] | Wis_p[131072] | Wss_p[196608] | bias_p[512]
    float* c_state = ws;
    float* Wis_p   = ws + 131072;
    float* Wss_p   = ws + 131072 + 131072;
    float* bias_p  = ws + 131072 + 131072 + 196608;

    pack_kernel<<<(HID * CIN * 4 * 3 + 255) / 256, 256, 0, stream>>>(
        W_is, b_is, W_ss, b_ss, Wis_p, Wss_p, bias_p);

    for (int r = 0; r < HDIM; ++r) {
        row_kernel<<<512, 256, 0, stream>>>(
            x, Wis_p, Wss_p, bias_p, c_state, out, r);
    }
}